// Round 4
// baseline (330.902 us; speedup 1.0000x reference)
//
#include <hip/hip_runtime.h>
#include <math.h>

// ---------------------------------------------------------------------------
// MultiheadAttention B=2,S=2048,D=1024,H=16,HD=64. I/O fp32; internal fp16 MFMA.
//   0) cvt: q,k,v,WQ..WO fp32 -> fp16, PLUS mask fp32 -> fp16*log2e
//      (into spare workspace when ws_size permits, else into dead d_out)
//   1) gemm_qkv (m97 staging, direct-store epilogue):
//      Q fp16 [B,H,S,64] pre-scaled by 0.125*log2e, K fp16 [B,H,S,64],
//      V fp16 transposed [B,H,64,S]
//   2) attn: transposed scores S^T = K Q^T, exp2 softmax, padded LDS,
//      in-block split-K x2 (512 thr), register-prefetch double-buffered
//      K/V/mask staging, P packed in-register into the PV B-operand.
//      R4: block covers 128 q-rows; each wave holds TWO Q-subtile register
//      sets (32 q/wave) so every K/V ds_read_b128 feeds 2x the MFMAs --
//      halves LDS-pipe demand per CU (the measured bottleneck; grid 512 =
//      2 blocks/CU). XCD remap REVERTED (R3: FETCH +33MB, dur +3.3us).
//      Mask enters as MFMA acc-init. Defer-max (THR=8). Two-pass epilogue.
//   3) gemm_o: AO @ WO^T + b -> d_out fp32
// ---------------------------------------------------------------------------

typedef _Float16 h8 __attribute__((ext_vector_type(8)));
typedef _Float16 h4 __attribute__((ext_vector_type(4)));
typedef float f4 __attribute__((ext_vector_type(4)));

#define MFMA16(a, b, c) __builtin_amdgcn_mfma_f32_16x16x32_f16((a), (b), (c), 0, 0, 0)
#define EXP2F(x) __builtin_amdgcn_exp2f(x)   // v_exp_f32 = 2^x

static constexpr int Bn = 2, Sn = 2048, Dn = 1024, Hn = 16, HDn = 64;
static constexpr int Mn = Bn * Sn;   // 4096
static constexpr int Kn = Dn;        // 1024
static constexpr int Nn = Dn;        // 1024
static constexpr int LDP = 72;       // LDS stride (64+8 pad): 36 dwords ≡ 4 (mod 32)
static constexpr float LOG2E = 1.4426950408889634f;

__device__ __forceinline__ void gload_lds16(const _Float16* g, _Float16* l) {
  // wave-uniform LDS base; HW scatters lane i -> base + i*16 bytes [m104]
  __builtin_amdgcn_global_load_lds(
      (const __attribute__((address_space(1))) unsigned int*)g,
      (__attribute__((address_space(3))) unsigned int*)l, 16, 0, 0);
}

// ------------------------------- cvt pass ----------------------------------
struct CvtJobs {
  const float* src[8];
  _Float16* dst[8];
  int n4[8];
  float scl[8];
};

__global__ __launch_bounds__(256) void cvt_kernel(CvtJobs j) {
  const int stride = gridDim.x * blockDim.x;
  const int t0 = blockIdx.x * blockDim.x + threadIdx.x;
#pragma unroll
  for (int k = 0; k < 8; ++k) {
    const float4* __restrict__ s = (const float4*)j.src[k];
    h4* __restrict__ d = (h4*)j.dst[k];
    const int n = j.n4[k];
    const float sc = j.scl[k];
    for (int i = t0; i < n; i += stride) {
      const float4 f = s[i];
      h4 h;
      h[0] = (_Float16)(f.x * sc); h[1] = (_Float16)(f.y * sc);
      h[2] = (_Float16)(f.z * sc); h[3] = (_Float16)(f.w * sc);
      d[i] = h;
    }
  }
}

// ------------------------------- QKV GEMM ----------------------------------
struct QkvArgs {
  const _Float16* X[3];
  const _Float16* W[3];
  const float* bias[3];
  _Float16* out[3];
};

// C = X @ W^T + bias. 128x128 tile, BK=64, 4 waves 2x2, m97 staging,
// direct-store epilogue.
// z=0: Q*0.125*log2e -> [B,H,S,64]; z=1: K -> [B,H,S,64]; z=2: V^T -> [B,H,64,S]
__global__ __launch_bounds__(256) void gemm_qkv(QkvArgs args) {
  const int z = blockIdx.z;
  const _Float16* __restrict__ X = args.X[z];
  const _Float16* __restrict__ W = args.W[z];
  const float* __restrict__ bias = args.bias[z];
  _Float16* __restrict__ out = args.out[z];

  __shared__ _Float16 As[128 * 64];
  __shared__ _Float16 Bs[128 * 64];

  const int t = threadIdx.x;
  const int lane = t & 63, wv = t >> 6;
  const int l15 = lane & 15, quad = lane >> 4;
  const int wm = (wv >> 1) * 64, wn = (wv & 1) * 64;
  const int n0 = blockIdx.x * 128, m0 = blockIdx.y * 128;

  f4 acc[4][4];
#pragma unroll
  for (int i = 0; i < 4; ++i)
#pragma unroll
    for (int j = 0; j < 4; ++j) {
      f4 zz = {0.f, 0.f, 0.f, 0.f};
      acc[i][j] = zz;
    }

  const int srow = lane >> 3, scol = (lane & 7) * 8;

  for (int k0 = 0; k0 < Kn; k0 += 64) {
    __syncthreads();
#pragma unroll
    for (int u = 0; u < 4; ++u) {
      const int s = wv * 4 + u;
      const int row = s * 8 + srow;
      gload_lds16(X + (size_t)(m0 + row) * Kn + k0 + scol, As + s * 512);
      gload_lds16(W + (size_t)(n0 + row) * Kn + k0 + scol, Bs + s * 512);
    }
    __syncthreads();
#pragma unroll
    for (int kk = 0; kk < 64; kk += 32) {
      h8 af[4], bfr[4];
#pragma unroll
      for (int i = 0; i < 4; ++i)
        af[i] = *(const h8*)&As[(wm + i * 16 + l15) * 64 + kk + quad * 8];
#pragma unroll
      for (int j = 0; j < 4; ++j)
        bfr[j] = *(const h8*)&Bs[(wn + j * 16 + l15) * 64 + kk + quad * 8];
#pragma unroll
      for (int i = 0; i < 4; ++i)
#pragma unroll
        for (int j = 0; j < 4; ++j)
          acc[i][j] = MFMA16(af[i], bfr[j], acc[i][j]);
    }
  }

  // ---- direct-store epilogue; C/D layout col=l15, row=quad*4+r [m89/m91] ----
  const float osc = (z == 0) ? (0.125f * LOG2E) : 1.0f;
  if (z != 2) {
#pragma unroll
    for (int j = 0; j < 4; ++j) {
      const int n = n0 + wn + j * 16 + l15;
      const float bvs = bias[n] * osc;
      const int hh = n >> 6, hd = n & 63;
#pragma unroll
      for (int i = 0; i < 4; ++i) {
        const int mb = m0 + wm + i * 16 + quad * 4;
        const int bb = mb >> 11;
#pragma unroll
        for (int r = 0; r < 4; ++r) {
          const int ss = (mb + r) & (Sn - 1);
          out[(((size_t)(bb * Hn + hh)) * Sn + ss) * HDn + hd] =
              (_Float16)(acc[i][j][r] * osc + bvs);
        }
      }
    }
  } else {
#pragma unroll
    for (int j = 0; j < 4; ++j) {
      const int n = n0 + wn + j * 16 + l15;
      const float bv = bias[n];
      const int hh = n >> 6, hd = n & 63;
#pragma unroll
      for (int i = 0; i < 4; ++i) {
        const int mb = m0 + wm + i * 16 + quad * 4;
        const int bb = mb >> 11, ss = mb & (Sn - 1);
        h4 hv;
#pragma unroll
        for (int r = 0; r < 4; ++r) hv[r] = (_Float16)(acc[i][j][r] + bv);
        *(h4*)(out + (((size_t)(bb * Hn + hh)) * HDn + hd) * Sn + ss) = hv;
      }
    }
  }
}

// ------------------------------- O GEMM ------------------------------------
__global__ __launch_bounds__(256) void gemm_o(const _Float16* __restrict__ X,
                                              const _Float16* __restrict__ W,
                                              const float* __restrict__ bias,
                                              float* __restrict__ out) {
  __shared__ _Float16 As[128 * 64];
  __shared__ _Float16 Bs[128 * 64];

  const int t = threadIdx.x;
  const int lane = t & 63, wv = t >> 6;
  const int l15 = lane & 15, quad = lane >> 4;
  const int wm = (wv >> 1) * 64, wn = (wv & 1) * 64;
  const int n0 = blockIdx.x * 128, m0 = blockIdx.y * 128;

  f4 acc[4][4];
#pragma unroll
  for (int i = 0; i < 4; ++i)
#pragma unroll
    for (int j = 0; j < 4; ++j) {
      f4 zz = {0.f, 0.f, 0.f, 0.f};
      acc[i][j] = zz;
    }

  const int srow = lane >> 3, scol = (lane & 7) * 8;

  for (int k0 = 0; k0 < Kn; k0 += 64) {
    __syncthreads();
#pragma unroll
    for (int u = 0; u < 4; ++u) {
      const int s = wv * 4 + u;
      const int row = s * 8 + srow;
      gload_lds16(X + (size_t)(m0 + row) * Kn + k0 + scol, As + s * 512);
      gload_lds16(W + (size_t)(n0 + row) * Kn + k0 + scol, Bs + s * 512);
    }
    __syncthreads();
#pragma unroll
    for (int kk = 0; kk < 64; kk += 32) {
      h8 af[4], bfr[4];
#pragma unroll
      for (int i = 0; i < 4; ++i)
        af[i] = *(const h8*)&As[(wm + i * 16 + l15) * 64 + kk + quad * 8];
#pragma unroll
      for (int j = 0; j < 4; ++j)
        bfr[j] = *(const h8*)&Bs[(wn + j * 16 + l15) * 64 + kk + quad * 8];
#pragma unroll
      for (int i = 0; i < 4; ++i)
#pragma unroll
        for (int j = 0; j < 4; ++j)
          acc[i][j] = MFMA16(af[i], bfr[j], acc[i][j]);
    }
  }

#pragma unroll
  for (int j = 0; j < 4; ++j) {
    const int n = n0 + wn + j * 16 + l15;
    const float bv = bias[n];
#pragma unroll
    for (int i = 0; i < 4; ++i) {
      const int mb = m0 + wm + i * 16 + quad * 4;
#pragma unroll
      for (int r = 0; r < 4; ++r)
        out[(size_t)(mb + r) * Nn + n] = acc[i][j][r] + bv;
    }
  }
}

// ------------------------------ attention ----------------------------------
// Transposed scores S^T = K Q^T (C col = l15 = q). 512 threads = 8 waves.
// Split-K x2: group g = wave>>2 handles keys [g*1024, g*1024+1024).
// Block covers 128 q-rows: wave wq (= w&3) owns q [wq*32, wq*32+32) as TWO
// 16-q register subtiles -- every K/V ds_read_b128 is reused by both
// subtiles' MFMAs (LDS traffic per q halved vs R1).
// Register-prefetch double-buffer: tile kt+1's K/V/mask global loads are
// issued right after tile kt's LDS is ready, consumed one full tile later.
//
// P never touches LDS: QK^T C-output s[ks][r] (key = 16ks+4quad+r, q = l15)
// packs directly into the PV B-operand; V is staged into LDS pre-permuted
// by pi (pos p holds key K: p5=K5,p4:3=K3:2,p2=K4,p1:0=K1:0) so PV A-reads
// are contiguous b128.
__global__ __launch_bounds__(512, 4) void attn_kernel(
    const _Float16* __restrict__ Qh,    // [B,H,S,64], pre-scaled by 0.125*log2e
    const _Float16* __restrict__ Kh,    // [B,H,S,64]
    const _Float16* __restrict__ Vt,    // [B,H,64,S]
    const _Float16* __restrict__ maskh, // [B,S,S] fp16, pre-scaled by log2e
    _Float16* __restrict__ out) {       // [B,S,1024] fp16
  __shared__ _Float16 smem[4 * 64 * LDP];  // K0,K1,V0,V1 (padded); combine reuses

  const int t = threadIdx.x;
  const int w = t >> 6, lane = t & 63;
  const int l15 = lane & 15, quad = lane >> 4;
  const int g = w >> 2;    // key-half group
  const int wq = w & 3;    // q-subtile-pair id (shared by pair w, w+4)

  const int bh = blockIdx.y;
  const int b = bh >> 4, h = bh & 15;
  const size_t headoff = (size_t)bh * Sn * HDn;
  const _Float16* Qp = Qh + headoff;
  const _Float16* Kp = Kh + headoff;
  const _Float16* Vp = Vt + headoff;

  const int qb = blockIdx.x * 128;
  const int q0 = qb + wq * 32;         // this wave: q [q0, q0+32)
  // Q as B-operand: n = l15 -> q, k = quad*8+j -> d. Two subtiles.
  const h8 qf00 = *(const h8*)(Qp + (size_t)(q0 + l15) * HDn + quad * 8);
  const h8 qf01 = *(const h8*)(Qp + (size_t)(q0 + l15) * HDn + 32 + quad * 8);
  const h8 qf10 = *(const h8*)(Qp + (size_t)(q0 + 16 + l15) * HDn + quad * 8);
  const h8 qf11 = *(const h8*)(Qp + (size_t)(q0 + 16 + l15) * HDn + 32 + quad * 8);

  const int kbase = g * (Sn / 2);
  const _Float16* mrow0 = maskh + ((size_t)b * Sn + q0 + l15) * Sn + kbase;
  const _Float16* mrow1 = mrow0 + (size_t)16 * Sn;

  float m_run0 = -INFINITY, l_part0 = 0.f;
  float m_run1 = -INFINITY, l_part1 = 0.f;
  f4 o0[4], o1[4];
#pragma unroll
  for (int nt = 0; nt < 4; ++nt) {
    f4 zz = {0.f, 0.f, 0.f, 0.f};
    o0[nt] = zz;
    o1[nt] = zz;
  }

  _Float16* Kg = smem + g * (64 * LDP);
  _Float16* Vg = smem + (2 + g) * (64 * LDP);

  const int tg = t & 255;  // staging index within group (4 waves = 256 threads)
  const int srow = tg >> 3, sc8 = (tg & 7) * 8;  // K chunk geometry (row, col)
  const int srow1 = srow + 32;                   // chunk 1: same col, +32 rows
  // V permuted base: keys 8a..8a+7 land at [vb..vb+3] and [vb+8..vb+11]
  const int a = tg & 7;
  const int vb = ((a >> 2) & 1) * 32 + (a & 1) * 16 + ((a >> 1) & 1) * 4;

  constexpr int NT = (Sn / 2) / 64;  // 16 tiles per group

  // ---- register prefetch buffers ----
  uint4 kreg0, kreg1, vreg0, vreg1;
  uint2 mreg0[4], mreg1[4];
  auto kv_issue = [&](int kt) {
    kreg0 = *(const uint4*)(Kp + (size_t)(kbase + kt * 64 + srow) * HDn + sc8);
    vreg0 = *(const uint4*)(Vp + (size_t)srow * Sn + kbase + kt * 64 + sc8);
    kreg1 = *(const uint4*)(Kp + (size_t)(kbase + kt * 64 + srow1) * HDn + sc8);
    vreg1 = *(const uint4*)(Vp + (size_t)srow1 * Sn + kbase + kt * 64 + sc8);
  };
  auto m_issue = [&](int kt) {
#pragma unroll
    for (int ks = 0; ks < 4; ++ks) {
      mreg0[ks] = *(const uint2*)(mrow0 + kt * 64 + ks * 16 + quad * 4);
      mreg1[ks] = *(const uint2*)(mrow1 + kt * 64 + ks * 16 + quad * 4);
    }
  };

  kv_issue(0);
  m_issue(0);

  for (int kt = 0; kt < NT; ++kt) {
    __syncthreads();  // all waves done reading previous tile's LDS
    // regs -> LDS (vmcnt waits on loads issued one full tile ago)
    *(uint4*)&Kg[srow * LDP + sc8] = kreg0;
    *(uint4*)&Kg[srow1 * LDP + sc8] = kreg1;
    // V: permuted-by-pi key positions, two b64 writes per 8-key chunk
    *(uint2*)&Vg[srow * LDP + vb] = make_uint2(vreg0.x, vreg0.y);
    *(uint2*)&Vg[srow * LDP + vb + 8] = make_uint2(vreg0.z, vreg0.w);
    *(uint2*)&Vg[srow1 * LDP + vb] = make_uint2(vreg1.x, vreg1.y);
    *(uint2*)&Vg[srow1 * LDP + vb + 8] = make_uint2(vreg1.z, vreg1.w);
    __syncthreads();  // tile ready
    const int nx = (kt + 1 < NT) ? kt + 1 : kt;
    kv_issue(nx);     // prefetch next tile; lands during this tile's compute

    // ---- S^T = K Q^T for BOTH q-subtiles: K fragments read ONCE ----
    f4 s0[4], s1[4];
#pragma unroll
    for (int ks = 0; ks < 4; ++ks) {
      const h8 kf0 = *(const h8*)&Kg[(ks * 16 + l15) * LDP + quad * 8];
      const h8 kf1 = *(const h8*)&Kg[(ks * 16 + l15) * LDP + 32 + quad * 8];
      const h4 mh0 = *(const h4*)&mreg0[ks];
      const h4 mh1 = *(const h4*)&mreg1[ks];
      f4 a0, a1;
#pragma unroll
      for (int r = 0; r < 4; ++r) { a0[r] = (float)mh0[r]; a1[r] = (float)mh1[r]; }
      a0 = MFMA16(kf0, qf00, a0);
      s0[ks] = MFMA16(kf1, qf01, a0);
      a1 = MFMA16(kf0, qf10, a1);
      s1[ks] = MFMA16(kf1, qf11, a1);
    }
    m_issue(nx);      // mreg consumed above; prefetch next tile's mask

    // ---- online softmax (exp2 domain), subtile 0; pack pf immediately ----
    h8 pf0[2], pf1[2];
    {
      float mx = s0[0][0];
#pragma unroll
      for (int ks = 0; ks < 4; ++ks)
#pragma unroll
        for (int r = 0; r < 4; ++r) mx = fmaxf(mx, s0[ks][r]);
      mx = fmaxf(mx, __shfl_xor(mx, 16));
      mx = fmaxf(mx, __shfl_xor(mx, 32));
      if (!__all(mx - m_run0 <= 8.0f)) {   // defer-max (T13)
        const float nm = fmaxf(m_run0, mx);
        const float al = EXP2F(m_run0 - nm);
        m_run0 = nm;
        l_part0 *= al;
#pragma unroll
        for (int nt = 0; nt < 4; ++nt)
#pragma unroll
          for (int r = 0; r < 4; ++r) o0[nt][r] *= al;
      }
      float sm = 0.f;
#pragma unroll
      for (int ks = 0; ks < 4; ++ks)
#pragma unroll
        for (int r = 0; r < 4; ++r) {
          s0[ks][r] = EXP2F(s0[ks][r] - m_run0);
          sm += s0[ks][r];
        }
      l_part0 += sm;
#pragma unroll
      for (int c = 0; c < 2; ++c)
#pragma unroll
        for (int r = 0; r < 4; ++r) {
          pf0[c][r] = (_Float16)s0[2 * c][r];
          pf0[c][4 + r] = (_Float16)s0[2 * c + 1][r];
        }
    }
    // ---- subtile 1 ----
    {
      float mx = s1[0][0];
#pragma unroll
      for (int ks = 0; ks < 4; ++ks)
#pragma unroll
        for (int r = 0; r < 4; ++r) mx = fmaxf(mx, s1[ks][r]);
      mx = fmaxf(mx, __shfl_xor(mx, 16));
      mx = fmaxf(mx, __shfl_xor(mx, 32));
      if (!__all(mx - m_run1 <= 8.0f)) {
        const float nm = fmaxf(m_run1, mx);
        const float al = EXP2F(m_run1 - nm);
        m_run1 = nm;
        l_part1 *= al;
#pragma unroll
        for (int nt = 0; nt < 4; ++nt)
#pragma unroll
          for (int r = 0; r < 4; ++r) o1[nt][r] *= al;
      }
      float sm = 0.f;
#pragma unroll
      for (int ks = 0; ks < 4; ++ks)
#pragma unroll
        for (int r = 0; r < 4; ++r) {
          s1[ks][r] = EXP2F(s1[ks][r] - m_run1);
          sm += s1[ks][r];
        }
      l_part1 += sm;
#pragma unroll
      for (int c = 0; c < 2; ++c)
#pragma unroll
        for (int r = 0; r < 4; ++r) {
          pf1[c][r] = (_Float16)s1[2 * c][r];
          pf1[c][4 + r] = (_Float16)s1[2 * c + 1][r];
        }
    }

    // ---- U^T += V^T P^T: V fragments read ONCE, feed both subtiles ----
#pragma unroll
    for (int c = 0; c < 2; ++c) {
#pragma unroll
      for (int nt = 0; nt < 4; ++nt) {
        const h8 vf = *(const h8*)&Vg[(nt * 16 + l15) * LDP + c * 32 + quad * 8];
        o0[nt] = MFMA16(vf, pf0[c], o0[nt]);
        o1[nt] = MFMA16(vf, pf1[c], o1[nt]);
      }
    }
  }

  // ---- quad-reduce l (deferred from the loop) ----
  l_part0 += __shfl_xor(l_part0, 16);
  l_part0 += __shfl_xor(l_part0, 32);
  l_part1 += __shfl_xor(l_part1, 16);
  l_part1 += __shfl_xor(l_part1, 32);

  // ---- flash combine across the two key halves (pair w <-> w+4) ----
  // Two passes (one per q-subtile) through the validated single-subtile path.
  float* Uex = (float*)smem;            // [pair][q=16][stride 72] fp32 (18.4 KB)
  float* mex = Uex + 4 * 16 * LDP;      // in V0 region
  float* lex = mex + 64;
#pragma unroll
  for (int sub = 0; sub < 2; ++sub) {
    const f4* oo = sub ? o1 : o0;
    const float mr = sub ? m_run1 : m_run0;
    const float lp = sub ? l_part1 : l_part0;
    const int q0s = q0 + sub * 16;
    __syncthreads();  // main-loop smem reads (sub=0) / Uex reads (sub=1) done
    if (g == 1) {
#pragma unroll
      for (int nt = 0; nt < 4; ++nt)
        *(f4*)&Uex[wq * 16 * LDP + l15 * LDP + nt * 16 + quad * 4] = oo[nt];
      if (quad == 0) {
        mex[wq * 16 + l15] = mr;
        lex[wq * 16 + l15] = lp;
      }
    }
    __syncthreads();
    if (g == 0) {
      const float m1 = mex[wq * 16 + l15];
      const float l1 = lex[wq * 16 + l15];
      const float mm = fmaxf(mr, m1);
      const float f0 = EXP2F(mr - mm);
      const float f1 = EXP2F(m1 - mm);
      const float rl = 1.0f / (f0 * lp + f1 * l1);
      // wave-private Ob staging lives in the (now idle) V1 region
      _Float16* Ob = smem + 3 * (64 * LDP) + (w * 16) * LDP;
#pragma unroll
      for (int nt = 0; nt < 4; ++nt) {
        const f4 Ur = *(const f4*)&Uex[wq * 16 * LDP + l15 * LDP + nt * 16 + quad * 4];
        h4 ov;
#pragma unroll
        for (int r = 0; r < 4; ++r)
          ov[r] = (_Float16)((oo[nt][r] * f0 + Ur[r] * f1) * rl);
        *(h4*)&Ob[l15 * LDP + nt * 16 + quad * 4] = ov;  // Ob[q_local][d]
      }
      // wave-private transpose -> coalesced stores (in-wave DS ordering, R4)
      const int qr = lane >> 2;            // 0..15
      const int seg = (lane & 3) * 16;     // 0,16,32,48
      _Float16* dst = out + ((size_t)b * Sn + q0s + qr) * Dn + h * 64 + seg;
      *(uint4*)dst = *(const uint4*)&Ob[qr * LDP + seg];
      *(uint4*)(dst + 8) = *(const uint4*)&Ob[qr * LDP + seg + 8];
    }
  }
}

// ------------------------------ launch -------------------------------------
extern "C" void kernel_launch(void* const* d_in, const int* in_sizes, int n_in,
                              void* d_out, int out_size, void* d_ws, size_t ws_size,
                              hipStream_t stream) {
  const float* q = (const float*)d_in[0];
  const float* k = (const float*)d_in[1];
  const float* v = (const float*)d_in[2];
  const float* mask = (const float*)d_in[3];
  const float* WQ = (const float*)d_in[4];
  const float* bQ = (const float*)d_in[5];
  const float* WK = (const float*)d_in[6];
  const float* bK = (const float*)d_in[7];
  const float* WV = (const float*)d_in[8];
  const float* bV = (const float*)d_in[9];
  const float* WO = (const float*)d_in[10];
  const float* bO = (const float*)d_in[11];

  _Float16* ws = (_Float16*)d_ws;
  const size_t MD = (size_t)Mn * Dn;   // 4.19M elems
  const size_t DD = (size_t)Dn * Dn;   // 1.05M
  const size_t SS = (size_t)Bn * Sn * Sn;  // 8.39M elems (mask fp16)
  _Float16* qh  = ws;
  _Float16* kh  = ws + MD;
  _Float16* vh  = ws + 2 * MD;
  _Float16* WQh = ws + 3 * MD;
  _Float16* WKh = WQh + DD;
  _Float16* WVh = WKh + DD;
  _Float16* WOh = WVh + DD;
  _Float16* Qh  = ws + 3 * MD + 4 * DD;
  _Float16* Kh  = Qh + MD;
  _Float16* Vt  = Kh + MD;
  _Float16* AO  = qh;  // qh dead after QKV gemm
  // mask fp16: prefer spare workspace after Vt; fall back to dead d_out
  // (B*S*S fp16 bytes == Mn*Dn fp32 bytes exactly; d_out dead until gemm_o)
  const size_t used = 6 * MD + 4 * DD;
  _Float16* Mh = (ws_size >= (used + SS) * sizeof(_Float16))
                     ? (ws + used)
                     : (_Float16*)d_out;

  CvtJobs cj;
  cj.src[0] = q;    cj.dst[0] = qh;  cj.n4[0] = (int)(MD / 4);  cj.scl[0] = 1.f;
  cj.src[1] = k;    cj.dst[1] = kh;  cj.n4[1] = (int)(MD / 4);  cj.scl[1] = 1.f;
  cj.src[2] = v;    cj.dst[2] = vh;  cj.n4[2] = (int)(MD / 4);  cj.scl[2] = 1.f;
  cj.src[3] = WQ;   cj.dst[3] = WQh; cj.n4[3] = (int)(DD / 4);  cj.scl[3] = 1.f;
  cj.src[4] = WK;   cj.dst[4] = WKh; cj.n4[4] = (int)(DD / 4);  cj.scl[4] = 1.f;
  cj.src[5] = WV;   cj.dst[5] = WVh; cj.n4[5] = (int)(DD / 4);  cj.scl[5] = 1.f;
  cj.src[6] = WO;   cj.dst[6] = WOh; cj.n4[6] = (int)(DD / 4);  cj.scl[6] = 1.f;
  cj.src[7] = mask; cj.dst[7] = Mh;  cj.n4[7] = (int)(SS / 4);  cj.scl[7] = LOG2E;
  cvt_kernel<<<1024, 256, 0, stream>>>(cj);

  QkvArgs ga;
  ga.X[0] = qh; ga.W[0] = WQh; ga.bias[0] = bQ; ga.out[0] = Qh;
  ga.X[1] = kh; ga.W[1] = WKh; ga.bias[1] = bK; ga.out[1] = Kh;
  ga.X[2] = vh; ga.W[2] = WVh; ga.bias[2] = bV; ga.out[2] = Vt;
  gemm_qkv<<<dim3(Nn / 128, Mn / 128, 3), 256, 0, stream>>>(ga);

  attn_kernel<<<dim3(Sn / 128, Bn * Hn), 512, 0, stream>>>(Qh, Kh, Vt, Mh, AO);

  gemm_o<<<dim3(Nn / 128, Mn / 128), 256, 0, stream>>>(AO, WOh, bO, (float*)d_out);
}

// Round 5
// 330.429 us; speedup vs baseline: 1.0014x; 1.0014x over previous
//
#include <hip/hip_runtime.h>
#include <math.h>

// ---------------------------------------------------------------------------
// MultiheadAttention B=2,S=2048,D=1024,H=16,HD=64. I/O fp32; internal fp16 MFMA.
//   0) cvt: q,k,v,WQ..WO fp32 -> fp16, PLUS mask fp32 -> fp16*log2e
//      (into spare workspace when ws_size permits, else into dead d_out)
//   1) gemm_qkv (m97 staging, direct-store epilogue):
//      Q fp16 [B,H,S,64] pre-scaled by 0.125*log2e, K fp16 [B,H,S,64],
//      V fp16 transposed [B,H,64,S]
//   2) attn: transposed scores S^T = K Q^T, exp2 softmax, padded LDS,
//      in-block split-K x2 (512 thr), register-prefetch double-buffered
//      K/V/mask staging, P packed in-register into the PV B-operand.
//      Block covers 128 q-rows; each wave holds TWO Q-subtile register sets
//      (32 q/wave) so every K/V ds_read_b128 feeds 2x the MFMAs -- halves
//      LDS-pipe demand per CU (the measured bottleneck; grid 512 = 2/CU).
//      R5 FIX vs R4: epilogue was `const f4* oo = sub ? o1 : o0` -- a
//      runtime pointer into register arrays (rule #20) that forced o0/o1
//      into scratch for the WHOLE main loop (WRITE_SIZE 8->29 MB, VGPR
//      collapsed to 64). Now expanded explicitly via macro; all indices
//      compile-time. Mask enters as MFMA acc-init. Defer-max (THR=8).
//   3) gemm_o: AO @ WO^T + b -> d_out fp32
// ---------------------------------------------------------------------------

typedef _Float16 h8 __attribute__((ext_vector_type(8)));
typedef _Float16 h4 __attribute__((ext_vector_type(4)));
typedef float f4 __attribute__((ext_vector_type(4)));

#define MFMA16(a, b, c) __builtin_amdgcn_mfma_f32_16x16x32_f16((a), (b), (c), 0, 0, 0)
#define EXP2F(x) __builtin_amdgcn_exp2f(x)   // v_exp_f32 = 2^x

static constexpr int Bn = 2, Sn = 2048, Dn = 1024, Hn = 16, HDn = 64;
static constexpr int Mn = Bn * Sn;   // 4096
static constexpr int Kn = Dn;        // 1024
static constexpr int Nn = Dn;        // 1024
static constexpr int LDP = 72;       // LDS stride (64+8 pad): 36 dwords ≡ 4 (mod 32)
static constexpr float LOG2E = 1.4426950408889634f;

__device__ __forceinline__ void gload_lds16(const _Float16* g, _Float16* l) {
  // wave-uniform LDS base; HW scatters lane i -> base + i*16 bytes [m104]
  __builtin_amdgcn_global_load_lds(
      (const __attribute__((address_space(1))) unsigned int*)g,
      (__attribute__((address_space(3))) unsigned int*)l, 16, 0, 0);
}

// ------------------------------- cvt pass ----------------------------------
struct CvtJobs {
  const float* src[8];
  _Float16* dst[8];
  int n4[8];
  float scl[8];
};

__global__ __launch_bounds__(256) void cvt_kernel(CvtJobs j) {
  const int stride = gridDim.x * blockDim.x;
  const int t0 = blockIdx.x * blockDim.x + threadIdx.x;
#pragma unroll
  for (int k = 0; k < 8; ++k) {
    const float4* __restrict__ s = (const float4*)j.src[k];
    h4* __restrict__ d = (h4*)j.dst[k];
    const int n = j.n4[k];
    const float sc = j.scl[k];
    for (int i = t0; i < n; i += stride) {
      const float4 f = s[i];
      h4 h;
      h[0] = (_Float16)(f.x * sc); h[1] = (_Float16)(f.y * sc);
      h[2] = (_Float16)(f.z * sc); h[3] = (_Float16)(f.w * sc);
      d[i] = h;
    }
  }
}

// ------------------------------- QKV GEMM ----------------------------------
struct QkvArgs {
  const _Float16* X[3];
  const _Float16* W[3];
  const float* bias[3];
  _Float16* out[3];
};

// C = X @ W^T + bias. 128x128 tile, BK=64, 4 waves 2x2, m97 staging,
// direct-store epilogue.
// z=0: Q*0.125*log2e -> [B,H,S,64]; z=1: K -> [B,H,S,64]; z=2: V^T -> [B,H,64,S]
__global__ __launch_bounds__(256) void gemm_qkv(QkvArgs args) {
  const int z = blockIdx.z;
  const _Float16* __restrict__ X = args.X[z];
  const _Float16* __restrict__ W = args.W[z];
  const float* __restrict__ bias = args.bias[z];
  _Float16* __restrict__ out = args.out[z];

  __shared__ _Float16 As[128 * 64];
  __shared__ _Float16 Bs[128 * 64];

  const int t = threadIdx.x;
  const int lane = t & 63, wv = t >> 6;
  const int l15 = lane & 15, quad = lane >> 4;
  const int wm = (wv >> 1) * 64, wn = (wv & 1) * 64;
  const int n0 = blockIdx.x * 128, m0 = blockIdx.y * 128;

  f4 acc[4][4];
#pragma unroll
  for (int i = 0; i < 4; ++i)
#pragma unroll
    for (int j = 0; j < 4; ++j) {
      f4 zz = {0.f, 0.f, 0.f, 0.f};
      acc[i][j] = zz;
    }

  const int srow = lane >> 3, scol = (lane & 7) * 8;

  for (int k0 = 0; k0 < Kn; k0 += 64) {
    __syncthreads();
#pragma unroll
    for (int u = 0; u < 4; ++u) {
      const int s = wv * 4 + u;
      const int row = s * 8 + srow;
      gload_lds16(X + (size_t)(m0 + row) * Kn + k0 + scol, As + s * 512);
      gload_lds16(W + (size_t)(n0 + row) * Kn + k0 + scol, Bs + s * 512);
    }
    __syncthreads();
#pragma unroll
    for (int kk = 0; kk < 64; kk += 32) {
      h8 af[4], bfr[4];
#pragma unroll
      for (int i = 0; i < 4; ++i)
        af[i] = *(const h8*)&As[(wm + i * 16 + l15) * 64 + kk + quad * 8];
#pragma unroll
      for (int j = 0; j < 4; ++j)
        bfr[j] = *(const h8*)&Bs[(wn + j * 16 + l15) * 64 + kk + quad * 8];
#pragma unroll
      for (int i = 0; i < 4; ++i)
#pragma unroll
        for (int j = 0; j < 4; ++j)
          acc[i][j] = MFMA16(af[i], bfr[j], acc[i][j]);
    }
  }

  // ---- direct-store epilogue; C/D layout col=l15, row=quad*4+r [m89/m91] ----
  const float osc = (z == 0) ? (0.125f * LOG2E) : 1.0f;
  if (z != 2) {
#pragma unroll
    for (int j = 0; j < 4; ++j) {
      const int n = n0 + wn + j * 16 + l15;
      const float bvs = bias[n] * osc;
      const int hh = n >> 6, hd = n & 63;
#pragma unroll
      for (int i = 0; i < 4; ++i) {
        const int mb = m0 + wm + i * 16 + quad * 4;
        const int bb = mb >> 11;
#pragma unroll
        for (int r = 0; r < 4; ++r) {
          const int ss = (mb + r) & (Sn - 1);
          out[(((size_t)(bb * Hn + hh)) * Sn + ss) * HDn + hd] =
              (_Float16)(acc[i][j][r] * osc + bvs);
        }
      }
    }
  } else {
#pragma unroll
    for (int j = 0; j < 4; ++j) {
      const int n = n0 + wn + j * 16 + l15;
      const float bv = bias[n];
      const int hh = n >> 6, hd = n & 63;
#pragma unroll
      for (int i = 0; i < 4; ++i) {
        const int mb = m0 + wm + i * 16 + quad * 4;
        const int bb = mb >> 11, ss = mb & (Sn - 1);
        h4 hv;
#pragma unroll
        for (int r = 0; r < 4; ++r) hv[r] = (_Float16)(acc[i][j][r] + bv);
        *(h4*)(out + (((size_t)(bb * Hn + hh)) * HDn + hd) * Sn + ss) = hv;
      }
    }
  }
}

// ------------------------------- O GEMM ------------------------------------
__global__ __launch_bounds__(256) void gemm_o(const _Float16* __restrict__ X,
                                              const _Float16* __restrict__ W,
                                              const float* __restrict__ bias,
                                              float* __restrict__ out) {
  __shared__ _Float16 As[128 * 64];
  __shared__ _Float16 Bs[128 * 64];

  const int t = threadIdx.x;
  const int lane = t & 63, wv = t >> 6;
  const int l15 = lane & 15, quad = lane >> 4;
  const int wm = (wv >> 1) * 64, wn = (wv & 1) * 64;
  const int n0 = blockIdx.x * 128, m0 = blockIdx.y * 128;

  f4 acc[4][4];
#pragma unroll
  for (int i = 0; i < 4; ++i)
#pragma unroll
    for (int j = 0; j < 4; ++j) {
      f4 zz = {0.f, 0.f, 0.f, 0.f};
      acc[i][j] = zz;
    }

  const int srow = lane >> 3, scol = (lane & 7) * 8;

  for (int k0 = 0; k0 < Kn; k0 += 64) {
    __syncthreads();
#pragma unroll
    for (int u = 0; u < 4; ++u) {
      const int s = wv * 4 + u;
      const int row = s * 8 + srow;
      gload_lds16(X + (size_t)(m0 + row) * Kn + k0 + scol, As + s * 512);
      gload_lds16(W + (size_t)(n0 + row) * Kn + k0 + scol, Bs + s * 512);
    }
    __syncthreads();
#pragma unroll
    for (int kk = 0; kk < 64; kk += 32) {
      h8 af[4], bfr[4];
#pragma unroll
      for (int i = 0; i < 4; ++i)
        af[i] = *(const h8*)&As[(wm + i * 16 + l15) * 64 + kk + quad * 8];
#pragma unroll
      for (int j = 0; j < 4; ++j)
        bfr[j] = *(const h8*)&Bs[(wn + j * 16 + l15) * 64 + kk + quad * 8];
#pragma unroll
      for (int i = 0; i < 4; ++i)
#pragma unroll
        for (int j = 0; j < 4; ++j)
          acc[i][j] = MFMA16(af[i], bfr[j], acc[i][j]);
    }
  }

#pragma unroll
  for (int j = 0; j < 4; ++j) {
    const int n = n0 + wn + j * 16 + l15;
    const float bv = bias[n];
#pragma unroll
    for (int i = 0; i < 4; ++i) {
      const int mb = m0 + wm + i * 16 + quad * 4;
#pragma unroll
      for (int r = 0; r < 4; ++r)
        out[(size_t)(mb + r) * Nn + n] = acc[i][j][r] + bv;
    }
  }
}

// ------------------------------ attention ----------------------------------
// Transposed scores S^T = K Q^T (C col = l15 = q). 512 threads = 8 waves.
// Split-K x2: group g = wave>>2 handles keys [g*1024, g*1024+1024).
// Block covers 128 q-rows: wave wq (= w&3) owns q [wq*32, wq*32+32) as TWO
// 16-q register subtiles -- every K/V ds_read_b128 is reused by both
// subtiles' MFMAs (LDS traffic per q halved vs the 64-q block).
// Register-prefetch double-buffer: tile kt+1's K/V/mask global loads are
// issued right after tile kt's LDS is ready, consumed one full tile later.
//
// P never touches LDS: QK^T C-output s[ks][r] (key = 16ks+4quad+r, q = l15)
// packs directly into the PV B-operand; V is staged into LDS pre-permuted
// by pi (pos p holds key K: p5=K5,p4:3=K3:2,p2=K4,p1:0=K1:0) so PV A-reads
// are contiguous b128.
//
// Flash-combine epilogue: EXPLICIT per-subtile expansion (macro, all
// compile-time indices) -- never form a pointer into register arrays.
#define COMBINE_SUB(OO, MR, LP, Q0S)                                          \
  do {                                                                        \
    __syncthreads(); /* prior smem reads done */                              \
    if (g == 1) {                                                             \
      _Pragma("unroll") for (int nt = 0; nt < 4; ++nt)                        \
          *(f4*)&Uex[wq * 16 * LDP + l15 * LDP + nt * 16 + quad * 4] =        \
              OO[nt];                                                         \
      if (quad == 0) {                                                        \
        mex[wq * 16 + l15] = (MR);                                            \
        lex[wq * 16 + l15] = (LP);                                            \
      }                                                                       \
    }                                                                         \
    __syncthreads();                                                          \
    if (g == 0) {                                                             \
      const float m1 = mex[wq * 16 + l15];                                    \
      const float l1 = lex[wq * 16 + l15];                                    \
      const float mm = fmaxf((MR), m1);                                       \
      const float f0 = EXP2F((MR)-mm);                                        \
      const float f1 = EXP2F(m1 - mm);                                        \
      const float rl = 1.0f / (f0 * (LP) + f1 * l1);                          \
      _Float16* Ob = smem + 3 * (64 * LDP) + (w * 16) * LDP;                  \
      _Pragma("unroll") for (int nt = 0; nt < 4; ++nt) {                      \
        const f4 Ur =                                                         \
            *(const f4*)&Uex[wq * 16 * LDP + l15 * LDP + nt * 16 + quad * 4]; \
        h4 ov;                                                                \
        _Pragma("unroll") for (int r = 0; r < 4; ++r) ov[r] =                 \
            (_Float16)((OO[nt][r] * f0 + Ur[r] * f1) * rl);                   \
        *(h4*)&Ob[l15 * LDP + nt * 16 + quad * 4] = ov;                       \
      }                                                                       \
      const int qr = lane >> 2;                                               \
      const int seg = (lane & 3) * 16;                                        \
      _Float16* dst = out + ((size_t)b * Sn + (Q0S) + qr) * Dn + h * 64 + seg;\
      *(uint4*)dst = *(const uint4*)&Ob[qr * LDP + seg];                      \
      *(uint4*)(dst + 8) = *(const uint4*)&Ob[qr * LDP + seg + 8];            \
    }                                                                         \
  } while (0)

__global__ __launch_bounds__(512, 4) void attn_kernel(
    const _Float16* __restrict__ Qh,    // [B,H,S,64], pre-scaled by 0.125*log2e
    const _Float16* __restrict__ Kh,    // [B,H,S,64]
    const _Float16* __restrict__ Vt,    // [B,H,64,S]
    const _Float16* __restrict__ maskh, // [B,S,S] fp16, pre-scaled by log2e
    _Float16* __restrict__ out) {       // [B,S,1024] fp16
  __shared__ _Float16 smem[4 * 64 * LDP];  // K0,K1,V0,V1 (padded); combine reuses

  const int t = threadIdx.x;
  const int w = t >> 6, lane = t & 63;
  const int l15 = lane & 15, quad = lane >> 4;
  const int g = w >> 2;    // key-half group
  const int wq = w & 3;    // q-subtile-pair id (shared by pair w, w+4)

  const int bh = blockIdx.y;
  const int b = bh >> 4, h = bh & 15;
  const size_t headoff = (size_t)bh * Sn * HDn;
  const _Float16* Qp = Qh + headoff;
  const _Float16* Kp = Kh + headoff;
  const _Float16* Vp = Vt + headoff;

  const int qb = blockIdx.x * 128;
  const int q0 = qb + wq * 32;         // this wave: q [q0, q0+32)
  // Q as B-operand: n = l15 -> q, k = quad*8+j -> d. Two subtiles.
  const h8 qf00 = *(const h8*)(Qp + (size_t)(q0 + l15) * HDn + quad * 8);
  const h8 qf01 = *(const h8*)(Qp + (size_t)(q0 + l15) * HDn + 32 + quad * 8);
  const h8 qf10 = *(const h8*)(Qp + (size_t)(q0 + 16 + l15) * HDn + quad * 8);
  const h8 qf11 = *(const h8*)(Qp + (size_t)(q0 + 16 + l15) * HDn + 32 + quad * 8);

  const int kbase = g * (Sn / 2);
  const _Float16* mrow0 = maskh + ((size_t)b * Sn + q0 + l15) * Sn + kbase;
  const _Float16* mrow1 = mrow0 + (size_t)16 * Sn;

  float m_run0 = -INFINITY, l_part0 = 0.f;
  float m_run1 = -INFINITY, l_part1 = 0.f;
  f4 o0[4], o1[4];
#pragma unroll
  for (int nt = 0; nt < 4; ++nt) {
    f4 zz = {0.f, 0.f, 0.f, 0.f};
    o0[nt] = zz;
    o1[nt] = zz;
  }

  _Float16* Kg = smem + g * (64 * LDP);
  _Float16* Vg = smem + (2 + g) * (64 * LDP);

  const int tg = t & 255;  // staging index within group (4 waves = 256 threads)
  const int srow = tg >> 3, sc8 = (tg & 7) * 8;  // K chunk geometry (row, col)
  const int srow1 = srow + 32;                   // chunk 1: same col, +32 rows
  // V permuted base: keys 8a..8a+7 land at [vb..vb+3] and [vb+8..vb+11]
  const int a = tg & 7;
  const int vb = ((a >> 2) & 1) * 32 + (a & 1) * 16 + ((a >> 1) & 1) * 4;

  constexpr int NT = (Sn / 2) / 64;  // 16 tiles per group

  // ---- register prefetch buffers ----
  uint4 kreg0, kreg1, vreg0, vreg1;
  uint2 mreg0[4], mreg1[4];
  auto kv_issue = [&](int kt) {
    kreg0 = *(const uint4*)(Kp + (size_t)(kbase + kt * 64 + srow) * HDn + sc8);
    vreg0 = *(const uint4*)(Vp + (size_t)srow * Sn + kbase + kt * 64 + sc8);
    kreg1 = *(const uint4*)(Kp + (size_t)(kbase + kt * 64 + srow1) * HDn + sc8);
    vreg1 = *(const uint4*)(Vp + (size_t)srow1 * Sn + kbase + kt * 64 + sc8);
  };
  auto m_issue = [&](int kt) {
#pragma unroll
    for (int ks = 0; ks < 4; ++ks) {
      mreg0[ks] = *(const uint2*)(mrow0 + kt * 64 + ks * 16 + quad * 4);
      mreg1[ks] = *(const uint2*)(mrow1 + kt * 64 + ks * 16 + quad * 4);
    }
  };

  kv_issue(0);
  m_issue(0);

  for (int kt = 0; kt < NT; ++kt) {
    __syncthreads();  // all waves done reading previous tile's LDS
    // regs -> LDS (vmcnt waits on loads issued one full tile ago)
    *(uint4*)&Kg[srow * LDP + sc8] = kreg0;
    *(uint4*)&Kg[srow1 * LDP + sc8] = kreg1;
    // V: permuted-by-pi key positions, two b64 writes per 8-key chunk
    *(uint2*)&Vg[srow * LDP + vb] = make_uint2(vreg0.x, vreg0.y);
    *(uint2*)&Vg[srow * LDP + vb + 8] = make_uint2(vreg0.z, vreg0.w);
    *(uint2*)&Vg[srow1 * LDP + vb] = make_uint2(vreg1.x, vreg1.y);
    *(uint2*)&Vg[srow1 * LDP + vb + 8] = make_uint2(vreg1.z, vreg1.w);
    __syncthreads();  // tile ready
    const int nx = (kt + 1 < NT) ? kt + 1 : kt;
    kv_issue(nx);     // prefetch next tile; lands during this tile's compute

    // ---- S^T = K Q^T for BOTH q-subtiles: K fragments read ONCE ----
    f4 s0[4], s1[4];
#pragma unroll
    for (int ks = 0; ks < 4; ++ks) {
      const h8 kf0 = *(const h8*)&Kg[(ks * 16 + l15) * LDP + quad * 8];
      const h8 kf1 = *(const h8*)&Kg[(ks * 16 + l15) * LDP + 32 + quad * 8];
      const h4 mh0 = *(const h4*)&mreg0[ks];
      const h4 mh1 = *(const h4*)&mreg1[ks];
      f4 a0, a1;
#pragma unroll
      for (int r = 0; r < 4; ++r) { a0[r] = (float)mh0[r]; a1[r] = (float)mh1[r]; }
      a0 = MFMA16(kf0, qf00, a0);
      s0[ks] = MFMA16(kf1, qf01, a0);
      a1 = MFMA16(kf0, qf10, a1);
      s1[ks] = MFMA16(kf1, qf11, a1);
    }
    m_issue(nx);      // mreg consumed above; prefetch next tile's mask

    // ---- online softmax (exp2 domain), subtile 0; pack pf immediately ----
    h8 pf0[2], pf1[2];
    {
      float mx = s0[0][0];
#pragma unroll
      for (int ks = 0; ks < 4; ++ks)
#pragma unroll
        for (int r = 0; r < 4; ++r) mx = fmaxf(mx, s0[ks][r]);
      mx = fmaxf(mx, __shfl_xor(mx, 16));
      mx = fmaxf(mx, __shfl_xor(mx, 32));
      if (!__all(mx - m_run0 <= 8.0f)) {   // defer-max (T13)
        const float nm = fmaxf(m_run0, mx);
        const float al = EXP2F(m_run0 - nm);
        m_run0 = nm;
        l_part0 *= al;
#pragma unroll
        for (int nt = 0; nt < 4; ++nt)
#pragma unroll
          for (int r = 0; r < 4; ++r) o0[nt][r] *= al;
      }
      float sm = 0.f;
#pragma unroll
      for (int ks = 0; ks < 4; ++ks)
#pragma unroll
        for (int r = 0; r < 4; ++r) {
          s0[ks][r] = EXP2F(s0[ks][r] - m_run0);
          sm += s0[ks][r];
        }
      l_part0 += sm;
#pragma unroll
      for (int c = 0; c < 2; ++c)
#pragma unroll
        for (int r = 0; r < 4; ++r) {
          pf0[c][r] = (_Float16)s0[2 * c][r];
          pf0[c][4 + r] = (_Float16)s0[2 * c + 1][r];
        }
    }
    // ---- subtile 1 ----
    {
      float mx = s1[0][0];
#pragma unroll
      for (int ks = 0; ks < 4; ++ks)
#pragma unroll
        for (int r = 0; r < 4; ++r) mx = fmaxf(mx, s1[ks][r]);
      mx = fmaxf(mx, __shfl_xor(mx, 16));
      mx = fmaxf(mx, __shfl_xor(mx, 32));
      if (!__all(mx - m_run1 <= 8.0f)) {
        const float nm = fmaxf(m_run1, mx);
        const float al = EXP2F(m_run1 - nm);
        m_run1 = nm;
        l_part1 *= al;
#pragma unroll
        for (int nt = 0; nt < 4; ++nt)
#pragma unroll
          for (int r = 0; r < 4; ++r) o1[nt][r] *= al;
      }
      float sm = 0.f;
#pragma unroll
      for (int ks = 0; ks < 4; ++ks)
#pragma unroll
        for (int r = 0; r < 4; ++r) {
          s1[ks][r] = EXP2F(s1[ks][r] - m_run1);
          sm += s1[ks][r];
        }
      l_part1 += sm;
#pragma unroll
      for (int c = 0; c < 2; ++c)
#pragma unroll
        for (int r = 0; r < 4; ++r) {
          pf1[c][r] = (_Float16)s1[2 * c][r];
          pf1[c][4 + r] = (_Float16)s1[2 * c + 1][r];
        }
    }

    // ---- U^T += V^T P^T: V fragments read ONCE, feed both subtiles ----
#pragma unroll
    for (int c = 0; c < 2; ++c) {
#pragma unroll
      for (int nt = 0; nt < 4; ++nt) {
        const h8 vf = *(const h8*)&Vg[(nt * 16 + l15) * LDP + c * 32 + quad * 8];
        o0[nt] = MFMA16(vf, pf0[c], o0[nt]);
        o1[nt] = MFMA16(vf, pf1[c], o1[nt]);
      }
    }
  }

  // ---- quad-reduce l (deferred from the loop) ----
  l_part0 += __shfl_xor(l_part0, 16);
  l_part0 += __shfl_xor(l_part0, 32);
  l_part1 += __shfl_xor(l_part1, 16);
  l_part1 += __shfl_xor(l_part1, 32);

  // ---- flash combine across the two key halves (pair w <-> w+4) ----
  // Explicit per-subtile expansion -- no pointers into register arrays.
  float* Uex = (float*)smem;            // [pair][q=16][stride 72] fp32 (18.4 KB)
  float* mex = Uex + 4 * 16 * LDP;      // in V0 region
  float* lex = mex + 64;
  COMBINE_SUB(o0, m_run0, l_part0, q0);
  COMBINE_SUB(o1, m_run1, l_part1, q0 + 16);
}

// ------------------------------ launch -------------------------------------
extern "C" void kernel_launch(void* const* d_in, const int* in_sizes, int n_in,
                              void* d_out, int out_size, void* d_ws, size_t ws_size,
                              hipStream_t stream) {
  const float* q = (const float*)d_in[0];
  const float* k = (const float*)d_in[1];
  const float* v = (const float*)d_in[2];
  const float* mask = (const float*)d_in[3];
  const float* WQ = (const float*)d_in[4];
  const float* bQ = (const float*)d_in[5];
  const float* WK = (const float*)d_in[6];
  const float* bK = (const float*)d_in[7];
  const float* WV = (const float*)d_in[8];
  const float* bV = (const float*)d_in[9];
  const float* WO = (const float*)d_in[10];
  const float* bO = (const float*)d_in[11];

  _Float16* ws = (_Float16*)d_ws;
  const size_t MD = (size_t)Mn * Dn;   // 4.19M elems
  const size_t DD = (size_t)Dn * Dn;   // 1.05M
  const size_t SS = (size_t)Bn * Sn * Sn;  // 8.39M elems (mask fp16)
  _Float16* qh  = ws;
  _Float16* kh  = ws + MD;
  _Float16* vh  = ws + 2 * MD;
  _Float16* WQh = ws + 3 * MD;
  _Float16* WKh = WQh + DD;
  _Float16* WVh = WKh + DD;
  _Float16* WOh = WVh + DD;
  _Float16* Qh  = ws + 3 * MD + 4 * DD;
  _Float16* Kh  = Qh + MD;
  _Float16* Vt  = Kh + MD;
  _Float16* AO  = qh;  // qh dead after QKV gemm
  // mask fp16: prefer spare workspace after Vt; fall back to dead d_out
  // (B*S*S fp16 bytes == Mn*Dn fp32 bytes exactly; d_out dead until gemm_o)
  const size_t used = 6 * MD + 4 * DD;
  _Float16* Mh = (ws_size >= (used + SS) * sizeof(_Float16))
                     ? (ws + used)
                     : (_Float16*)d_out;

  CvtJobs cj;
  cj.src[0] = q;    cj.dst[0] = qh;  cj.n4[0] = (int)(MD / 4);  cj.scl[0] = 1.f;
  cj.src[1] = k;    cj.dst[1] = kh;  cj.n4[1] = (int)(MD / 4);  cj.scl[1] = 1.f;
  cj.src[2] = v;    cj.dst[2] = vh;  cj.n4[2] = (int)(MD / 4);  cj.scl[2] = 1.f;
  cj.src[3] = WQ;   cj.dst[3] = WQh; cj.n4[3] = (int)(DD / 4);  cj.scl[3] = 1.f;
  cj.src[4] = WK;   cj.dst[4] = WKh; cj.n4[4] = (int)(DD / 4);  cj.scl[4] = 1.f;
  cj.src[5] = WV;   cj.dst[5] = WVh; cj.n4[5] = (int)(DD / 4);  cj.scl[5] = 1.f;
  cj.src[6] = WO;   cj.dst[6] = WOh; cj.n4[6] = (int)(DD / 4);  cj.scl[6] = 1.f;
  cj.src[7] = mask; cj.dst[7] = Mh;  cj.n4[7] = (int)(SS / 4);  cj.scl[7] = LOG2E;
  cvt_kernel<<<1024, 256, 0, stream>>>(cj);

  QkvArgs ga;
  ga.X[0] = qh; ga.W[0] = WQh; ga.bias[0] = bQ; ga.out[0] = Qh;
  ga.X[1] = kh; ga.W[1] = WKh; ga.bias[1] = bK; ga.out[1] = Kh;
  ga.X[2] = vh; ga.W[2] = WVh; ga.bias[2] = bV; ga.out[2] = Vt;
  gemm_qkv<<<dim3(Nn / 128, Mn / 128, 3), 256, 0, stream>>>(ga);

  attn_kernel<<<dim3(Sn / 128, Bn * Hn), 512, 0, stream>>>(Qh, Kh, Vt, Mh, AO);

  gemm_o<<<dim3(Nn / 128, Mn / 128), 256, 0, stream>>>(AO, WOh, bO, (float*)d_out);
}

// Round 7
// 301.526 us; speedup vs baseline: 1.0974x; 1.0959x over previous
//
#include <hip/hip_runtime.h>
#include <math.h>

// ---------------------------------------------------------------------------
// MultiheadAttention B=2,S=2048,D=1024,H=16,HD=64. I/O fp32; internal fp16 MFMA.
//   0) cvt: q,k,v,WQ..WO fp32 -> fp16, PLUS mask fp32 -> fp16*log2e
//      (into spare workspace when ws_size permits, else into dead d_out)
//   1) gemm_qkv (m97 staging, direct-store epilogue):
//      Q fp16 [B,H,S,64] pre-scaled by 0.125*log2e, K fp16 [B,H,S,64],
//      V fp16 transposed [B,H,64,S]
//   2) attn: R1-proven main loop (64-q blocks, 1024 blocks = 4/CU, VGPR 64),
//      transposed scores S^T = K Q^T, exp2 softmax, padded LDS, in-block
//      split-K x2 (512 thr), register-prefetch double-buffered K/V/mask
//      staging, P packed in-register into the PV B-operand.
//      T4 counted vmcnt: in-loop barriers are
//      `s_waitcnt lgkmcnt(0); s_barrier` inline asm -- NOT __syncthreads()
//      (which drains vmcnt(0) and forces all 12 in-flight prefetch loads,
//      incl. L3/HBM-latency mask reads, to land at EVERY barrier, twice per
//      tile). LDS ordering needs only lgkmcnt; the compiler emits precise
//      per-use vmcnt for kreg/mreg consumers, so prefetches span barriers.
//      R4/R5 lesson: kernel is latency/barrier-bound, NOT LDS-pipe-bound
//      (halving LDS traffic left total MFMA/VALU cycles identical, dur up).
//      (R6 bench was an infra failure -- "container failed twice", same
//      signature as R2 which passed on identical resubmit; hang audit clean:
//      s_barrier needs no drained counters, uniform control flow.)
//   3) gemm_o: AO @ WO^T + b -> d_out fp32
// ---------------------------------------------------------------------------

typedef _Float16 h8 __attribute__((ext_vector_type(8)));
typedef _Float16 h4 __attribute__((ext_vector_type(4)));
typedef float f4 __attribute__((ext_vector_type(4)));

#define MFMA16(a, b, c) __builtin_amdgcn_mfma_f32_16x16x32_f16((a), (b), (c), 0, 0, 0)
#define EXP2F(x) __builtin_amdgcn_exp2f(x)   // v_exp_f32 = 2^x
// Workgroup barrier WITHOUT the vmcnt(0) drain __syncthreads would emit.
// LDS visibility needs lgkmcnt(0) only; vm deps are handled per-use by the
// compiler's own counted waits (T4). Uniform control flow in the main loop.
#define BARRIER_LDS() asm volatile("s_waitcnt lgkmcnt(0)\n\ts_barrier" ::: "memory")

static constexpr int Bn = 2, Sn = 2048, Dn = 1024, Hn = 16, HDn = 64;
static constexpr int Mn = Bn * Sn;   // 4096
static constexpr int Kn = Dn;        // 1024
static constexpr int Nn = Dn;        // 1024
static constexpr int LDP = 72;       // LDS stride (64+8 pad): 36 dwords ≡ 4 (mod 32)
static constexpr float LOG2E = 1.4426950408889634f;

__device__ __forceinline__ void gload_lds16(const _Float16* g, _Float16* l) {
  // wave-uniform LDS base; HW scatters lane i -> base + i*16 bytes [m104]
  __builtin_amdgcn_global_load_lds(
      (const __attribute__((address_space(1))) unsigned int*)g,
      (__attribute__((address_space(3))) unsigned int*)l, 16, 0, 0);
}

// ------------------------------- cvt pass ----------------------------------
struct CvtJobs {
  const float* src[8];
  _Float16* dst[8];
  int n4[8];
  float scl[8];
};

__global__ __launch_bounds__(256) void cvt_kernel(CvtJobs j) {
  const int stride = gridDim.x * blockDim.x;
  const int t0 = blockIdx.x * blockDim.x + threadIdx.x;
#pragma unroll
  for (int k = 0; k < 8; ++k) {
    const float4* __restrict__ s = (const float4*)j.src[k];
    h4* __restrict__ d = (h4*)j.dst[k];
    const int n = j.n4[k];
    const float sc = j.scl[k];
    for (int i = t0; i < n; i += stride) {
      const float4 f = s[i];
      h4 h;
      h[0] = (_Float16)(f.x * sc); h[1] = (_Float16)(f.y * sc);
      h[2] = (_Float16)(f.z * sc); h[3] = (_Float16)(f.w * sc);
      d[i] = h;
    }
  }
}

// ------------------------------- QKV GEMM ----------------------------------
struct QkvArgs {
  const _Float16* X[3];
  const _Float16* W[3];
  const float* bias[3];
  _Float16* out[3];
};

// C = X @ W^T + bias. 128x128 tile, BK=64, 4 waves 2x2, m97 staging,
// direct-store epilogue.
// z=0: Q*0.125*log2e -> [B,H,S,64]; z=1: K -> [B,H,S,64]; z=2: V^T -> [B,H,64,S]
__global__ __launch_bounds__(256) void gemm_qkv(QkvArgs args) {
  const int z = blockIdx.z;
  const _Float16* __restrict__ X = args.X[z];
  const _Float16* __restrict__ W = args.W[z];
  const float* __restrict__ bias = args.bias[z];
  _Float16* __restrict__ out = args.out[z];

  __shared__ _Float16 As[128 * 64];
  __shared__ _Float16 Bs[128 * 64];

  const int t = threadIdx.x;
  const int lane = t & 63, wv = t >> 6;
  const int l15 = lane & 15, quad = lane >> 4;
  const int wm = (wv >> 1) * 64, wn = (wv & 1) * 64;
  const int n0 = blockIdx.x * 128, m0 = blockIdx.y * 128;

  f4 acc[4][4];
#pragma unroll
  for (int i = 0; i < 4; ++i)
#pragma unroll
    for (int j = 0; j < 4; ++j) {
      f4 zz = {0.f, 0.f, 0.f, 0.f};
      acc[i][j] = zz;
    }

  const int srow = lane >> 3, scol = (lane & 7) * 8;

  for (int k0 = 0; k0 < Kn; k0 += 64) {
    __syncthreads();
#pragma unroll
    for (int u = 0; u < 4; ++u) {
      const int s = wv * 4 + u;
      const int row = s * 8 + srow;
      gload_lds16(X + (size_t)(m0 + row) * Kn + k0 + scol, As + s * 512);
      gload_lds16(W + (size_t)(n0 + row) * Kn + k0 + scol, Bs + s * 512);
    }
    __syncthreads();
#pragma unroll
    for (int kk = 0; kk < 64; kk += 32) {
      h8 af[4], bfr[4];
#pragma unroll
      for (int i = 0; i < 4; ++i)
        af[i] = *(const h8*)&As[(wm + i * 16 + l15) * 64 + kk + quad * 8];
#pragma unroll
      for (int j = 0; j < 4; ++j)
        bfr[j] = *(const h8*)&Bs[(wn + j * 16 + l15) * 64 + kk + quad * 8];
#pragma unroll
      for (int i = 0; i < 4; ++i)
#pragma unroll
        for (int j = 0; j < 4; ++j)
          acc[i][j] = MFMA16(af[i], bfr[j], acc[i][j]);
    }
  }

  // ---- direct-store epilogue; C/D layout col=l15, row=quad*4+r [m89/m91] ----
  const float osc = (z == 0) ? (0.125f * LOG2E) : 1.0f;
  if (z != 2) {
#pragma unroll
    for (int j = 0; j < 4; ++j) {
      const int n = n0 + wn + j * 16 + l15;
      const float bvs = bias[n] * osc;
      const int hh = n >> 6, hd = n & 63;
#pragma unroll
      for (int i = 0; i < 4; ++i) {
        const int mb = m0 + wm + i * 16 + quad * 4;
        const int bb = mb >> 11;
#pragma unroll
        for (int r = 0; r < 4; ++r) {
          const int ss = (mb + r) & (Sn - 1);
          out[(((size_t)(bb * Hn + hh)) * Sn + ss) * HDn + hd] =
              (_Float16)(acc[i][j][r] * osc + bvs);
        }
      }
    }
  } else {
#pragma unroll
    for (int j = 0; j < 4; ++j) {
      const int n = n0 + wn + j * 16 + l15;
      const float bv = bias[n];
      const int hh = n >> 6, hd = n & 63;
#pragma unroll
      for (int i = 0; i < 4; ++i) {
        const int mb = m0 + wm + i * 16 + quad * 4;
        const int bb = mb >> 11, ss = mb & (Sn - 1);
        h4 hv;
#pragma unroll
        for (int r = 0; r < 4; ++r) hv[r] = (_Float16)(acc[i][j][r] + bv);
        *(h4*)(out + (((size_t)(bb * Hn + hh)) * HDn + hd) * Sn + ss) = hv;
      }
    }
  }
}

// ------------------------------- O GEMM ------------------------------------
__global__ __launch_bounds__(256) void gemm_o(const _Float16* __restrict__ X,
                                              const _Float16* __restrict__ W,
                                              const float* __restrict__ bias,
                                              float* __restrict__ out) {
  __shared__ _Float16 As[128 * 64];
  __shared__ _Float16 Bs[128 * 64];

  const int t = threadIdx.x;
  const int lane = t & 63, wv = t >> 6;
  const int l15 = lane & 15, quad = lane >> 4;
  const int wm = (wv >> 1) * 64, wn = (wv & 1) * 64;
  const int n0 = blockIdx.x * 128, m0 = blockIdx.y * 128;

  f4 acc[4][4];
#pragma unroll
  for (int i = 0; i < 4; ++i)
#pragma unroll
    for (int j = 0; j < 4; ++j) {
      f4 zz = {0.f, 0.f, 0.f, 0.f};
      acc[i][j] = zz;
    }

  const int srow = lane >> 3, scol = (lane & 7) * 8;

  for (int k0 = 0; k0 < Kn; k0 += 64) {
    __syncthreads();
#pragma unroll
    for (int u = 0; u < 4; ++u) {
      const int s = wv * 4 + u;
      const int row = s * 8 + srow;
      gload_lds16(X + (size_t)(m0 + row) * Kn + k0 + scol, As + s * 512);
      gload_lds16(W + (size_t)(n0 + row) * Kn + k0 + scol, Bs + s * 512);
    }
    __syncthreads();
#pragma unroll
    for (int kk = 0; kk < 64; kk += 32) {
      h8 af[4], bfr[4];
#pragma unroll
      for (int i = 0; i < 4; ++i)
        af[i] = *(const h8*)&As[(wm + i * 16 + l15) * 64 + kk + quad * 8];
#pragma unroll
      for (int j = 0; j < 4; ++j)
        bfr[j] = *(const h8*)&Bs[(wn + j * 16 + l15) * 64 + kk + quad * 8];
#pragma unroll
      for (int i = 0; i < 4; ++i)
#pragma unroll
        for (int j = 0; j < 4; ++j)
          acc[i][j] = MFMA16(af[i], bfr[j], acc[i][j]);
    }
  }

#pragma unroll
  for (int j = 0; j < 4; ++j) {
    const int n = n0 + wn + j * 16 + l15;
    const float bv = bias[n];
#pragma unroll
    for (int i = 0; i < 4; ++i) {
      const int mb = m0 + wm + i * 16 + quad * 4;
#pragma unroll
      for (int r = 0; r < 4; ++r)
        out[(size_t)(mb + r) * Nn + n] = acc[i][j][r] + bv;
    }
  }
}

// ------------------------------ attention ----------------------------------
// Transposed scores S^T = K Q^T (C col = l15 = q). 512 threads = 8 waves.
// Split-K x2: group g = wave>>2 handles keys [g*1024, g*1024+1024).
// Register-prefetch double-buffer: tile kt+1's K/V/mask global loads are
// issued right after tile kt's LDS is ready, consumed one full tile later.
// In-loop barriers are counted-vmcnt style (BARRIER_LDS: lgkmcnt(0)+s_barrier,
// NO vmcnt drain) so those prefetches stay in flight across barriers.
//
// P never touches LDS: QK^T C-output s[ks][r] (key = 16ks+4quad+r, q = l15)
// packs directly into the PV B-operand; V is staged into LDS pre-permuted
// by pi (pos p holds key K: p5=K5,p4:3=K3:2,p2=K4,p1:0=K1:0) so PV A-reads
// are contiguous b128.
__global__ __launch_bounds__(512) void attn_kernel(
    const _Float16* __restrict__ Qh,    // [B,H,S,64], pre-scaled by 0.125*log2e
    const _Float16* __restrict__ Kh,    // [B,H,S,64]
    const _Float16* __restrict__ Vt,    // [B,H,64,S]
    const _Float16* __restrict__ maskh, // [B,S,S] fp16, pre-scaled by log2e
    _Float16* __restrict__ out) {       // [B,S,1024] fp16
  __shared__ _Float16 smem[4 * 64 * LDP];  // K0,K1,V0,V1 (padded); combine reuses

  const int t = threadIdx.x;
  const int w = t >> 6, lane = t & 63;
  const int l15 = lane & 15, quad = lane >> 4;
  const int g = w >> 2;    // key-half group
  const int wq = w & 3;    // q-subtile id (shared by pair w, w+4)

  const int bh = blockIdx.y;
  const int b = bh >> 4, h = bh & 15;
  const size_t headoff = (size_t)bh * Sn * HDn;
  const _Float16* Qp = Qh + headoff;
  const _Float16* Kp = Kh + headoff;
  const _Float16* Vp = Vt + headoff;

  const int qb = blockIdx.x * 64;
  const int q0 = qb + wq * 16;
  // Q as B-operand: n = l15 -> q, k = quad*8+j -> d
  const h8 qf0 = *(const h8*)(Qp + (size_t)(q0 + l15) * HDn + quad * 8);
  const h8 qf1 = *(const h8*)(Qp + (size_t)(q0 + l15) * HDn + 32 + quad * 8);

  const int kbase = g * (Sn / 2);
  const _Float16* mrow = maskh + ((size_t)b * Sn + q0 + l15) * Sn + kbase;

  float m_run = -INFINITY, l_part = 0.f;  // l lane-partial; quad-reduced at end
  f4 o_acc[4];
#pragma unroll
  for (int nt = 0; nt < 4; ++nt) {
    f4 zz = {0.f, 0.f, 0.f, 0.f};
    o_acc[nt] = zz;
  }

  _Float16* Kg = smem + g * (64 * LDP);
  _Float16* Vg = smem + (2 + g) * (64 * LDP);

  const int tg = t & 255;  // staging index within group (4 waves = 256 threads)
  const int srow = tg >> 3, sc8 = (tg & 7) * 8;  // K chunk geometry (row, col)
  const int srow1 = srow + 32;                   // chunk 1: same col, +32 rows
  // V permuted base: keys 8a..8a+7 land at [vb..vb+3] and [vb+8..vb+11]
  const int a = tg & 7;
  const int vb = ((a >> 2) & 1) * 32 + (a & 1) * 16 + ((a >> 1) & 1) * 4;

  constexpr int NT = (Sn / 2) / 64;  // 16 tiles per group

  // ---- register prefetch buffers ----
  uint4 kreg0, kreg1, vreg0, vreg1;
  uint2 mreg[4];
  auto kv_issue = [&](int kt) {
    kreg0 = *(const uint4*)(Kp + (size_t)(kbase + kt * 64 + srow) * HDn + sc8);
    vreg0 = *(const uint4*)(Vp + (size_t)srow * Sn + kbase + kt * 64 + sc8);
    kreg1 = *(const uint4*)(Kp + (size_t)(kbase + kt * 64 + srow1) * HDn + sc8);
    vreg1 = *(const uint4*)(Vp + (size_t)srow1 * Sn + kbase + kt * 64 + sc8);
  };
  auto m_issue = [&](int kt) {
#pragma unroll
    for (int ks = 0; ks < 4; ++ks)
      mreg[ks] = *(const uint2*)(mrow + kt * 64 + ks * 16 + quad * 4);
  };

  kv_issue(0);
  m_issue(0);

  for (int kt = 0; kt < NT; ++kt) {
    BARRIER_LDS();    // all waves done reading previous tile's LDS (no vm drain)
    // regs -> LDS (compiler emits precise vmcnt for kreg/vreg deps only)
    *(uint4*)&Kg[srow * LDP + sc8] = kreg0;
    *(uint4*)&Kg[srow1 * LDP + sc8] = kreg1;
    // V: permuted-by-pi key positions, two b64 writes per 8-key chunk
    *(uint2*)&Vg[srow * LDP + vb] = make_uint2(vreg0.x, vreg0.y);
    *(uint2*)&Vg[srow * LDP + vb + 8] = make_uint2(vreg0.z, vreg0.w);
    *(uint2*)&Vg[srow1 * LDP + vb] = make_uint2(vreg1.x, vreg1.y);
    *(uint2*)&Vg[srow1 * LDP + vb + 8] = make_uint2(vreg1.z, vreg1.w);
    BARRIER_LDS();    // tile ready (writes visible; prefetches stay in flight)
    const int nx = (kt + 1 < NT) ? kt + 1 : kt;
    kv_issue(nx);     // prefetch next tile; lands during this tile's compute

    // ---- S^T = K Q^T: rows = keys (quad*4+r), cols = q (l15) ----
    // mask (fp16, pre-scaled by log2e) enters as the MFMA accumulator init.
    f4 s[4];
#pragma unroll
    for (int ks = 0; ks < 4; ++ks) {
      const h4 mh = *(const h4*)&mreg[ks];
      f4 acc0;
#pragma unroll
      for (int r = 0; r < 4; ++r) acc0[r] = (float)mh[r];
      const h8 kf0 = *(const h8*)&Kg[(ks * 16 + l15) * LDP + quad * 8];
      const h8 kf1 = *(const h8*)&Kg[(ks * 16 + l15) * LDP + 32 + quad * 8];
      acc0 = MFMA16(kf0, qf0, acc0);
      s[ks] = MFMA16(kf1, qf1, acc0);
    }
    m_issue(nx);      // mreg consumed above; prefetch next tile's mask

    // ---- per-lane online softmax (exp2 domain); l stays lane-partial ----
    float mx = s[0][0];
#pragma unroll
    for (int ks = 0; ks < 4; ++ks)
#pragma unroll
      for (int r = 0; r < 4; ++r) mx = fmaxf(mx, s[ks][r]);
    mx = fmaxf(mx, __shfl_xor(mx, 16));
    mx = fmaxf(mx, __shfl_xor(mx, 32));
    // defer-max (T13): only rescale when the running max grows by > 8
    // (P then bounded by 2^8 = 256 -- safe in fp16/fp32 headroom)
    if (!__all(mx - m_run <= 8.0f)) {
      const float nm = fmaxf(m_run, mx);
      const float alpha = EXP2F(m_run - nm);
      m_run = nm;
      l_part *= alpha;
#pragma unroll
      for (int nt = 0; nt < 4; ++nt)
#pragma unroll
        for (int r = 0; r < 4; ++r) o_acc[nt][r] *= alpha;
    }
    float sm = 0.f;
#pragma unroll
    for (int ks = 0; ks < 4; ++ks)
#pragma unroll
      for (int r = 0; r < 4; ++r) {
        s[ks][r] = EXP2F(s[ks][r] - m_run);
        sm += s[ks][r];
      }
    l_part += sm;

    // ---- U^T += V^T P^T: P packed in-register as B-operand (no LDS) ----
#pragma unroll
    for (int c = 0; c < 2; ++c) {
      h8 pf;
#pragma unroll
      for (int r = 0; r < 4; ++r) pf[r] = (_Float16)s[2 * c][r];
#pragma unroll
      for (int r = 0; r < 4; ++r) pf[4 + r] = (_Float16)s[2 * c + 1][r];
#pragma unroll
      for (int nt = 0; nt < 4; ++nt) {
        const h8 vf = *(const h8*)&Vg[(nt * 16 + l15) * LDP + c * 32 + quad * 8];
        o_acc[nt] = MFMA16(vf, pf, o_acc[nt]);
      }
    }
  }

  // ---- quad-reduce l (deferred from the loop) ----
  l_part += __shfl_xor(l_part, 16);
  l_part += __shfl_xor(l_part, 32);

  // ---- flash combine across the two key halves (pair w <-> w+4) ----
  __syncthreads();  // full drain OK here (one-time epilogue); reuse smem fp32
  float* Uex = (float*)smem;            // [pair][q=16][stride 72] fp32
  float* mex = Uex + 4 * 16 * LDP;      // 4*16*72 = 4608 floats
  float* lex = mex + 64;
  if (g == 1) {
#pragma unroll
    for (int nt = 0; nt < 4; ++nt)
      *(f4*)&Uex[wq * 16 * LDP + l15 * LDP + nt * 16 + quad * 4] = o_acc[nt];
    if (quad == 0) {
      mex[wq * 16 + l15] = m_run;
      lex[wq * 16 + l15] = l_part;
    }
  }
  __syncthreads();
  if (g == 0) {
    const float m1 = mex[wq * 16 + l15];
    const float l1 = lex[wq * 16 + l15];
    const float mm = fmaxf(m_run, m1);
    const float f0 = EXP2F(m_run - mm);
    const float f1 = EXP2F(m1 - mm);
    const float rl = 1.0f / (f0 * l_part + f1 * l1);
    // wave-private Ob staging lives in the (now idle) V1 region
    _Float16* Ob = smem + 3 * (64 * LDP) + (w * 16) * LDP;
#pragma unroll
    for (int nt = 0; nt < 4; ++nt) {
      const f4 Ur = *(const f4*)&Uex[wq * 16 * LDP + l15 * LDP + nt * 16 + quad * 4];
      h4 ov;
#pragma unroll
      for (int r = 0; r < 4; ++r)
        ov[r] = (_Float16)((o_acc[nt][r] * f0 + Ur[r] * f1) * rl);
      *(h4*)&Ob[l15 * LDP + nt * 16 + quad * 4] = ov;  // Ob[q_local][d]
    }
    // wave-private transpose -> coalesced stores (in-wave DS ordering, R4)
    const int qr = lane >> 2;            // 0..15
    const int seg = (lane & 3) * 16;     // 0,16,32,48
    _Float16* dst = out + ((size_t)b * Sn + q0 + qr) * Dn + h * 64 + seg;
    *(uint4*)dst = *(const uint4*)&Ob[qr * LDP + seg];
    *(uint4*)(dst + 8) = *(const uint4*)&Ob[qr * LDP + seg + 8];
  }
}

// ------------------------------ launch -------------------------------------
extern "C" void kernel_launch(void* const* d_in, const int* in_sizes, int n_in,
                              void* d_out, int out_size, void* d_ws, size_t ws_size,
                              hipStream_t stream) {
  const float* q = (const float*)d_in[0];
  const float* k = (const float*)d_in[1];
  const float* v = (const float*)d_in[2];
  const float* mask = (const float*)d_in[3];
  const float* WQ = (const float*)d_in[4];
  const float* bQ = (const float*)d_in[5];
  const float* WK = (const float*)d_in[6];
  const float* bK = (const float*)d_in[7];
  const float* WV = (const float*)d_in[8];
  const float* bV = (const float*)d_in[9];
  const float* WO = (const float*)d_in[10];
  const float* bO = (const float*)d_in[11];

  _Float16* ws = (_Float16*)d_ws;
  const size_t MD = (size_t)Mn * Dn;   // 4.19M elems
  const size_t DD = (size_t)Dn * Dn;   // 1.05M
  const size_t SS = (size_t)Bn * Sn * Sn;  // 8.39M elems (mask fp16)
  _Float16* qh  = ws;
  _Float16* kh  = ws + MD;
  _Float16* vh  = ws + 2 * MD;
  _Float16* WQh = ws + 3 * MD;
  _Float16* WKh = WQh + DD;
  _Float16* WVh = WKh + DD;
  _Float16* WOh = WVh + DD;
  _Float16* Qh  = ws + 3 * MD + 4 * DD;
  _Float16* Kh  = Qh + MD;
  _Float16* Vt  = Kh + MD;
  _Float16* AO  = qh;  // qh dead after QKV gemm
  // mask fp16: prefer spare workspace after Vt; fall back to dead d_out
  // (B*S*S fp16 bytes == Mn*Dn fp32 bytes exactly; d_out dead until gemm_o)
  const size_t used = 6 * MD + 4 * DD;
  _Float16* Mh = (ws_size >= (used + SS) * sizeof(_Float16))
                     ? (ws + used)
                     : (_Float16*)d_out;

  CvtJobs cj;
  cj.src[0] = q;    cj.dst[0] = qh;  cj.n4[0] = (int)(MD / 4);  cj.scl[0] = 1.f;
  cj.src[1] = k;    cj.dst[1] = kh;  cj.n4[1] = (int)(MD / 4);  cj.scl[1] = 1.f;
  cj.src[2] = v;    cj.dst[2] = vh;  cj.n4[2] = (int)(MD / 4);  cj.scl[2] = 1.f;
  cj.src[3] = WQ;   cj.dst[3] = WQh; cj.n4[3] = (int)(DD / 4);  cj.scl[3] = 1.f;
  cj.src[4] = WK;   cj.dst[4] = WKh; cj.n4[4] = (int)(DD / 4);  cj.scl[4] = 1.f;
  cj.src[5] = WV;   cj.dst[5] = WVh; cj.n4[5] = (int)(DD / 4);  cj.scl[5] = 1.f;
  cj.src[6] = WO;   cj.dst[6] = WOh; cj.n4[6] = (int)(DD / 4);  cj.scl[6] = 1.f;
  cj.src[7] = mask; cj.dst[7] = Mh;  cj.n4[7] = (int)(SS / 4);  cj.scl[7] = LOG2E;
  cvt_kernel<<<1024, 256, 0, stream>>>(cj);

  QkvArgs ga;
  ga.X[0] = qh; ga.W[0] = WQh; ga.bias[0] = bQ; ga.out[0] = Qh;
  ga.X[1] = kh; ga.W[1] = WKh; ga.bias[1] = bK; ga.out[1] = Kh;
  ga.X[2] = vh; ga.W[2] = WVh; ga.bias[2] = bV; ga.out[2] = Vt;
  gemm_qkv<<<dim3(Nn / 128, Mn / 128, 3), 256, 0, stream>>>(ga);

  attn_kernel<<<dim3(Sn / 64, Bn * Hn), 512, 0, stream>>>(Qh, Kh, Vt, Mh, AO);

  gemm_o<<<dim3(Nn / 128, Mn / 128), 256, 0, stream>>>(AO, WOh, bO, (float*)d_out);
}